// Round 8
// baseline (75.745 us; speedup 1.0000x reference)
//
#include <hip/hip_runtime.h>

// Chamfer distance via bf16 split-MFMA.
//   d(p,q') = ||p||^2 + (||q'||^2 - 2 p.q')
// Rank-16 GEMM in bf16 hi/lo-split form; one v_mfma_f32_32x32x16_bf16 =
// 32 targets x 32 queries = 1024 pairs.
// R5/R7 lesson: MFMA C/D lived in AGPRs; constant-zero C was rematerialized
// (v_accvgpr_write x16) per MFMA and D read back (v_accvgpr_read x16) ->
// ~34 extra VALU ops/MFMA (VALU busy 44us vs 15us of real fold work).
// R8 fix: opaque runtime zero C (asm-touched, built once -> can't remat),
// unroll 1 to cap in-flight D tuples, fold D 16->4 immediately (12 ops) into
// 4 running accumulators per frag (4 ops) = 16 VALU/MFMA, low pressure.
// R6 lesson (kept): no inline-asm reads of MFMA results -- folds are plain
// fminf so the compiler inserts MFMA->VALU hazard waits.

typedef __attribute__((ext_vector_type(8))) short  s16x8;
typedef __attribute__((ext_vector_type(16))) float f32x16;

#define TSLICE 1024   // targets staged in LDS per block (32 KB packed)
#define QPB    512    // queries per block (4 waves x 128)
#define QPW    128    // queries per wave (4 frags of 32)

// ---------- bf16 split helper (bit-level, RNE) ----------
__device__ inline unsigned int bf16bits(float v, float &hival) {
    unsigned int u = __float_as_uint(v);
    unsigned int r = (u + 0x7FFFu + ((u >> 16) & 1u)) >> 16;
    hival = __uint_as_float(r << 16);
    return r;
}

// ---------- fused pre-pass: pack both inputs + sentinel-init d_out ----------
__global__ __launch_bounds__(256)
void pack_all_kernel(const float* __restrict__ in1, const float* __restrict__ in2,
                     ushort* __restrict__ A1, ushort* __restrict__ B1, float* __restrict__ S1,
                     ushort* __restrict__ A2, ushort* __restrict__ B2, float* __restrict__ S2,
                     unsigned int* __restrict__ out, int P1, int P2) {
    const int g = blockIdx.x * 256 + threadIdx.x;
    if (g >= P1 + P2) return;
    out[g] = 0x7F7F7F7Fu;                 // 3.39e38f sentinel (flat over both outs)

    const float* src; ushort* pA; ushort* pB; float* sq; int p;
    if (g < P1) { src = in1; pA = A1; pB = B1; sq = S1; p = g; }
    else        { src = in2; pA = A2; pB = B2; sq = S2; p = g - P1; }

    const float x = src[3*p+0], y = src[3*p+1], z = src[3*p+2];
    float xhf, xlf, yhf, ylf, zhf, zlf, shf, tmp;
    const ushort xh = (ushort)bf16bits(x, xhf);
    const ushort xl = (ushort)bf16bits(x - xhf, xlf);
    const ushort yh = (ushort)bf16bits(y, yhf);
    const ushort yl = (ushort)bf16bits(y - yhf, ylf);
    const ushort zh = (ushort)bf16bits(z, zhf);
    const ushort zl = (ushort)bf16bits(z - zhf, zlf);
    const float s = fmaf(x, x, fmaf(y, y, z * z));
    const ushort sh = (ushort)bf16bits(s, shf);
    const ushort sl = (ushort)bf16bits(s - shf, tmp);
    const ushort m2xh = (ushort)bf16bits(-2.0f * xhf, tmp);
    const ushort m2xl = (ushort)bf16bits(-2.0f * xlf, tmp);
    const ushort m2yh = (ushort)bf16bits(-2.0f * yhf, tmp);
    const ushort m2yl = (ushort)bf16bits(-2.0f * ylf, tmp);
    const ushort m2zh = (ushort)bf16bits(-2.0f * zhf, tmp);
    const ushort m2zl = (ushort)bf16bits(-2.0f * zlf, tmp);
    const ushort ONE = 0x3F80;

    const s16x8 a0 = {(short)m2xh,(short)m2xl,(short)m2xh,(short)m2xl,
                      (short)m2yh,(short)m2yl,(short)m2yh,(short)m2yl};
    const s16x8 a1 = {(short)m2zh,(short)m2zl,(short)m2zh,(short)m2zl,
                      (short)sh,  (short)sl,  0, 0};
    const s16x8 b0 = {(short)xh,(short)xh,(short)xl,(short)xl,
                      (short)yh,(short)yh,(short)yl,(short)yl};
    const s16x8 b1 = {(short)zh,(short)zh,(short)zl,(short)zl,
                      (short)ONE,(short)ONE, 0, 0};

    s16x8* A8 = (s16x8*)pA;
    s16x8* B8 = (s16x8*)pB;
    // A: fragment-linear per 32-target tile: chunk = tilebase*64 + khalf*32 + row
    const int c0 = (p & ~31) * 2 + (p & 31);
    A8[c0]      = a0;   // k-slots 0-7  (lanes 0-31)
    A8[c0 + 32] = a1;   // k-slots 8-15 (lanes 32-63)
    // B: point-major
    B8[2*p]     = b0;
    B8[2*p + 1] = b1;
    sq[p] = s;
}

// ---------- main MFMA kernel, both directions (blockIdx.z selects) ----------
__global__ __launch_bounds__(256, 2)
void chamfer_mfma_kernel(const ushort* __restrict__ Ad1, const ushort* __restrict__ Bd1,
                         const float*  __restrict__ Sd1, unsigned int* __restrict__ Od1,
                         const ushort* __restrict__ Ad2, const ushort* __restrict__ Bd2,
                         const float*  __restrict__ Sd2, unsigned int* __restrict__ Od2,
                         int Np, int Mp) {
    __shared__ s16x8 lds8[TSLICE * 2];   // 32 KB
    const int z = blockIdx.z;
    const ushort* pA  = z ? Ad2 : Ad1;
    const ushort* pB  = z ? Bd2 : Bd1;
    const float*  sqq = z ? Sd2 : Sd1;
    unsigned int* out = z ? Od2 : Od1;

    const int tid  = threadIdx.x;
    const int lane = tid & 63;
    const int wid  = tid >> 6;
    const int qblock = blockIdx.x * QPB;        // flat over B*Np (QPB | Np)
    const int b = qblock / Np;
    const size_t gchunk = ((size_t)b * Mp + (size_t)blockIdx.y * TSLICE) * 2;
    const s16x8* gA = (const s16x8*)pA + gchunk;
    for (int i = tid; i < TSLICE * 2; i += 256) lds8[i] = gA[i];

    // B fragments: 4 x 32 queries, loop-invariant in registers
    const int qw = qblock + wid * QPW;
    s16x8 bfr[4];
    #pragma unroll
    for (int f = 0; f < 4; ++f) {
        const int q = qw + f * 32 + (lane & 31);
        bfr[f] = *(const s16x8*)(pB + (size_t)q * 16 + (size_t)(lane >> 5) * 8);
    }
    __syncthreads();

    // Opaque runtime zero: compiler cannot rematerialize the C tile per MFMA.
    float z0 = 0.0f;
    asm volatile("" : "+v"(z0));
    f32x16 cz;
    #pragma unroll
    for (int i = 0; i < 16; ++i) cz[i] = z0;

    float bests4[4][4];
    #pragma unroll
    for (int f = 0; f < 4; ++f)
        #pragma unroll
        for (int r = 0; r < 4; ++r) bests4[f][r] = 3.0e38f;

    const int NT = TSLICE / 32;
    #pragma unroll 1
    for (int t = 0; t < NT; ++t) {
        const s16x8 a = lds8[t * 64 + lane];
        #pragma unroll
        for (int f = 0; f < 4; ++f) {
            const f32x16 d = __builtin_amdgcn_mfma_f32_32x32x16_bf16(a, bfr[f], cz, 0, 0, 0);
            // fold 16 -> 4 (12 ops), then 4 running updates: 16 VALU / MFMA
            const float q0 = fminf(fminf(d[0],  d[1]),  fminf(d[2],  d[3]));
            const float q1 = fminf(fminf(d[4],  d[5]),  fminf(d[6],  d[7]));
            const float q2 = fminf(fminf(d[8],  d[9]),  fminf(d[10], d[11]));
            const float q3 = fminf(fminf(d[12], d[13]), fminf(d[14], d[15]));
            bests4[f][0] = fminf(bests4[f][0], q0);
            bests4[f][1] = fminf(bests4[f][1], q1);
            bests4[f][2] = fminf(bests4[f][2], q2);
            bests4[f][3] = fminf(bests4[f][3], q3);
        }
    }

    #pragma unroll
    for (int f = 0; f < 4; ++f) {
        float v = fminf(fminf(bests4[f][0], bests4[f][1]),
                        fminf(bests4[f][2], bests4[f][3]));
        v = fminf(v, __shfl_xor(v, 32));                      // merge row halves
        const int q = qw + f * 32 + (lane & 31);
        v = fmaxf(v + sqq[q], 0.0f);                          // clamp: keep >= 0
        if (lane < 32) atomicMin(out + q, __float_as_uint(v));
    }
}

// ---------- fallback (round-2 VALU kernel) if ws too small ----------
#define FSLICE 512
#define FROWS  512
__global__ __launch_bounds__(256)
void chamfer_dir_kernel(const float* __restrict__ P, const float* __restrict__ Q,
                        unsigned int* __restrict__ out, int Np, int Mp) {
    __shared__ float4 lds[FSLICE];
    const int tid = threadIdx.x;
    const int rowBase = blockIdx.x * FROWS;
    const int b = rowBase / Np;
    const int slice0 = blockIdx.y * FSLICE;
    const float* qs = Q + ((size_t)b * Mp + slice0) * 3;
    #pragma unroll
    for (int i = tid; i < FSLICE; i += 256) {
        const float x = qs[3*i+0], y = qs[3*i+1], z = qs[3*i+2];
        lds[i] = make_float4(x, y, z, fmaf(x, x, fmaf(y, y, z * z)));
    }
    const int q0 = rowBase + tid, q1 = q0 + 256;
    const float* p0 = P + (size_t)q0 * 3;
    const float* p1 = P + (size_t)q1 * 3;
    const float x0=p0[0], y0=p0[1], z0=p0[2], x1=p1[0], y1=p1[1], z1=p1[2];
    const float m2x0=-2*x0, m2y0=-2*y0, m2z0=-2*z0, m2x1=-2*x1, m2y1=-2*y1, m2z1=-2*z1;
    const float sqp0 = fmaf(x0,x0,fmaf(y0,y0,z0*z0));
    const float sqp1 = fmaf(x1,x1,fmaf(y1,y1,z1*z1));
    __syncthreads();
    float best0 = 3.0e38f, best1 = 3.0e38f;
    #pragma unroll 4
    for (int j = 0; j < FSLICE; j += 2) {
        const float4 a = lds[j], c = lds[j+1];
        const float d00 = fmaf(m2x0,a.x,fmaf(m2y0,a.y,fmaf(m2z0,a.z,a.w)));
        const float d01 = fmaf(m2x0,c.x,fmaf(m2y0,c.y,fmaf(m2z0,c.z,c.w)));
        best0 = fminf(fminf(d00,d01), best0);
        const float d10 = fmaf(m2x1,a.x,fmaf(m2y1,a.y,fmaf(m2z1,a.z,a.w)));
        const float d11 = fmaf(m2x1,c.x,fmaf(m2y1,c.y,fmaf(m2z1,c.z,c.w)));
        best1 = fminf(fminf(d10,d11), best1);
    }
    atomicMin(out + q0, __float_as_uint(fmaxf(best0 + sqp0, 0.f)));
    atomicMin(out + q1, __float_as_uint(fmaxf(best1 + sqp1, 0.f)));
}

extern "C" void kernel_launch(void* const* d_in, const int* in_sizes, int n_in,
                              void* d_out, int out_size, void* d_ws, size_t ws_size,
                              hipStream_t stream) {
    const float* in1 = (const float*)d_in[0];   // [B, N, 3]
    const float* in2 = (const float*)d_in[1];   // [B, M, 3]
    const int B = 8;
    const int N = in_sizes[0] / (B * 3);
    const int M = in_sizes[1] / (B * 3);
    const int P1 = B * N, P2 = B * M;
    unsigned int* out = (unsigned int*)d_out;

    const size_t packBytes1 = (size_t)P1 * 32, packBytes2 = (size_t)P2 * 32;
    const size_t need = 2*packBytes1 + 2*packBytes2 + (size_t)(P1+P2)*4;

    if (ws_size >= need && N == M) {
        char* w = (char*)d_ws;
        ushort* A1 = (ushort*)(w);
        ushort* B1 = (ushort*)(w + packBytes1);
        ushort* A2 = (ushort*)(w + 2*packBytes1);
        ushort* B2 = (ushort*)(w + 2*packBytes1 + packBytes2);
        float*  S1 = (float*) (w + 2*packBytes1 + 2*packBytes2);
        float*  S2 = (float*) (w + 2*packBytes1 + 2*packBytes2 + (size_t)P1*4);

        pack_all_kernel<<<(P1 + P2 + 255)/256, 256, 0, stream>>>(
            in1, in2, A1, B1, S1, A2, B2, S2, out, P1, P2);

        // z=0: dist1 (queries=input1, targets=input2); z=1: dist2
        dim3 g(P1 / QPB, M / TSLICE, 2);
        chamfer_mfma_kernel<<<g, 256, 0, stream>>>(
            A2, B1, S1, out,        // dir 1
            A1, B2, S2, out + P1,   // dir 2
            N, M);
    } else {
        hipMemsetAsync(d_out, 0x7F, (size_t)out_size * sizeof(float), stream);
        dim3 g1(P1 / FROWS, M / FSLICE);
        chamfer_dir_kernel<<<g1, 256, 0, stream>>>(in1, in2, out, N, M);
        dim3 g2(P2 / FROWS, N / FSLICE);
        chamfer_dir_kernel<<<g2, 256, 0, stream>>>(in2, in1, out + P1, M, N);
    }
}

// Round 9
// 59.701 us; speedup vs baseline: 1.2687x; 1.2687x over previous
//
#include <hip/hip_runtime.h>

// Chamfer distance via bf16 split-MFMA.
//   d(p,q') = ||p||^2 + (||q'||^2 + 512 - 2 p.q') - 512
// Rank-15 GEMM in bf16 hi/lo-split form; one v_mfma_f32_32x32x16_bf16 =
// 32 targets x 32 queries = 1024 pairs. The +512 bias K-slot makes every
// MFMA output positive, so the 16->1 min-fold runs as UNSIGNED INT min3
// (v_min3_u32 fusion is flag-free; bit order == float order for x>=0):
// 8 compiler-visible VALU ops per MFMA, hazard-safe (R6 lesson: no inline
// asm reading MFMA results).
// R8 lesson: don't pin C in arch VGPRs (forces per-MFMA accvgpr copies) and
// don't unroll-pin the t-loop. R5 config (default launch_bounds) was best.
// R9: TSLICE 512 (16 KB LDS) -> up to 10 blocks/CU; occupancy was the limit
// (34%, per-wave mfma->fold serial chain exposed).

typedef __attribute__((ext_vector_type(8))) short  s16x8;
typedef __attribute__((ext_vector_type(16))) float f32x16;
typedef unsigned int u32;

#define TSLICE 512    // targets staged in LDS per block (16 KB packed)
#define QPB    512    // queries per block (4 waves x 128)
#define QPW    128    // queries per wave (4 frags of 32)

__device__ inline u32 umin3(u32 a, u32 b, u32 c) {
    const u32 t = a < b ? a : b;
    return t < c ? t : c;           // -> v_min3_u32
}

// ---------- bf16 split helper (bit-level, RNE) ----------
__device__ inline unsigned int bf16bits(float v, float &hival) {
    unsigned int u = __float_as_uint(v);
    unsigned int r = (u + 0x7FFFu + ((u >> 16) & 1u)) >> 16;
    hival = __uint_as_float(r << 16);
    return r;
}

// ---------- fused pre-pass: pack both inputs + sentinel-init d_out ----------
__global__ __launch_bounds__(256)
void pack_all_kernel(const float* __restrict__ in1, const float* __restrict__ in2,
                     ushort* __restrict__ A1, ushort* __restrict__ B1, float* __restrict__ S1,
                     ushort* __restrict__ A2, ushort* __restrict__ B2, float* __restrict__ S2,
                     unsigned int* __restrict__ out, int P1, int P2) {
    const int g = blockIdx.x * 256 + threadIdx.x;
    if (g >= P1 + P2) return;
    out[g] = 0x7F7F7F7Fu;                 // 3.39e38f sentinel (flat over both outs)

    const float* src; ushort* pA; ushort* pB; float* sq; int p;
    if (g < P1) { src = in1; pA = A1; pB = B1; sq = S1; p = g; }
    else        { src = in2; pA = A2; pB = B2; sq = S2; p = g - P1; }

    const float x = src[3*p+0], y = src[3*p+1], z = src[3*p+2];
    float xhf, xlf, yhf, ylf, zhf, zlf, shf, tmp;
    const ushort xh = (ushort)bf16bits(x, xhf);
    const ushort xl = (ushort)bf16bits(x - xhf, xlf);
    const ushort yh = (ushort)bf16bits(y, yhf);
    const ushort yl = (ushort)bf16bits(y - yhf, ylf);
    const ushort zh = (ushort)bf16bits(z, zhf);
    const ushort zl = (ushort)bf16bits(z - zhf, zlf);
    const float s = fmaf(x, x, fmaf(y, y, z * z));
    const ushort sh = (ushort)bf16bits(s, shf);
    const ushort sl = (ushort)bf16bits(s - shf, tmp);
    const ushort m2xh = (ushort)bf16bits(-2.0f * xhf, tmp);
    const ushort m2xl = (ushort)bf16bits(-2.0f * xlf, tmp);
    const ushort m2yh = (ushort)bf16bits(-2.0f * yhf, tmp);
    const ushort m2yl = (ushort)bf16bits(-2.0f * ylf, tmp);
    const ushort m2zh = (ushort)bf16bits(-2.0f * zhf, tmp);
    const ushort m2zl = (ushort)bf16bits(-2.0f * zlf, tmp);
    const ushort ONE  = 0x3F80;           // 1.0 bf16
    const ushort BIAS = 0x4400;           // 512.0 bf16 (exact)

    const s16x8 a0 = {(short)m2xh,(short)m2xl,(short)m2xh,(short)m2xl,
                      (short)m2yh,(short)m2yl,(short)m2yh,(short)m2yl};
    const s16x8 a1 = {(short)m2zh,(short)m2zl,(short)m2zh,(short)m2zl,
                      (short)sh,  (short)sl,  (short)BIAS, 0};
    const s16x8 b0 = {(short)xh,(short)xh,(short)xl,(short)xl,
                      (short)yh,(short)yh,(short)yl,(short)yl};
    const s16x8 b1 = {(short)zh,(short)zh,(short)zl,(short)zl,
                      (short)ONE,(short)ONE,(short)ONE, 0};

    s16x8* A8 = (s16x8*)pA;
    s16x8* B8 = (s16x8*)pB;
    // A: fragment-linear per 32-target tile: chunk = tilebase*64 + khalf*32 + row
    const int c0 = (p & ~31) * 2 + (p & 31);
    A8[c0]      = a0;   // k-slots 0-7  (lanes 0-31)
    A8[c0 + 32] = a1;   // k-slots 8-15 (lanes 32-63)
    // B: point-major
    B8[2*p]     = b0;
    B8[2*p + 1] = b1;
    sq[p] = s;
}

// ---------- main MFMA kernel, both directions (blockIdx.z selects) ----------
__global__ __launch_bounds__(256)
void chamfer_mfma_kernel(const ushort* __restrict__ Ad1, const ushort* __restrict__ Bd1,
                         const float*  __restrict__ Sd1, unsigned int* __restrict__ Od1,
                         const ushort* __restrict__ Ad2, const ushort* __restrict__ Bd2,
                         const float*  __restrict__ Sd2, unsigned int* __restrict__ Od2,
                         int Np, int Mp) {
    __shared__ s16x8 lds8[TSLICE * 2];   // 16 KB
    const int z = blockIdx.z;
    const ushort* pA  = z ? Ad2 : Ad1;
    const ushort* pB  = z ? Bd2 : Bd1;
    const float*  sqq = z ? Sd2 : Sd1;
    unsigned int* out = z ? Od2 : Od1;

    const int tid  = threadIdx.x;
    const int lane = tid & 63;
    const int wid  = tid >> 6;
    const int qblock = blockIdx.x * QPB;        // flat over B*Np (QPB | Np)
    const int b = qblock / Np;
    const size_t gchunk = ((size_t)b * Mp + (size_t)blockIdx.y * TSLICE) * 2;
    const s16x8* gA = (const s16x8*)pA + gchunk;
    for (int i = tid; i < TSLICE * 2; i += 256) lds8[i] = gA[i];

    // B fragments: 4 x 32 queries, loop-invariant in registers
    const int qw = qblock + wid * QPW;
    s16x8 bfr[4];
    #pragma unroll
    for (int f = 0; f < 4; ++f) {
        const int q = qw + f * 32 + (lane & 31);
        bfr[f] = *(const s16x8*)(pB + (size_t)q * 16 + (size_t)(lane >> 5) * 8);
    }
    __syncthreads();

    const f32x16 cz = {0.f,0.f,0.f,0.f,0.f,0.f,0.f,0.f,
                       0.f,0.f,0.f,0.f,0.f,0.f,0.f,0.f};
    u32 bests[4] = {0x7F7F7F7Fu, 0x7F7F7F7Fu, 0x7F7F7F7Fu, 0x7F7F7F7Fu};

    const int NT = TSLICE / 32;
    for (int t = 0; t < NT; ++t) {
        const s16x8 a = lds8[t * 64 + lane];
        #pragma unroll
        for (int f = 0; f < 4; ++f) {
            const f32x16 d = __builtin_amdgcn_mfma_f32_32x32x16_bf16(a, bfr[f], cz, 0, 0, 0);
            // all outputs > 0 (bias) -> uint bit order == float order.
            // 16 -> 1 in 8 v_min3_u32 (integer min3 fusion is flag-free).
            const u32 m0 = umin3(__float_as_uint(d[0]),  __float_as_uint(d[1]),  __float_as_uint(d[2]));
            const u32 m1 = umin3(__float_as_uint(d[3]),  __float_as_uint(d[4]),  __float_as_uint(d[5]));
            const u32 m2 = umin3(__float_as_uint(d[6]),  __float_as_uint(d[7]),  __float_as_uint(d[8]));
            const u32 m3 = umin3(__float_as_uint(d[9]),  __float_as_uint(d[10]), __float_as_uint(d[11]));
            const u32 m4 = umin3(__float_as_uint(d[12]), __float_as_uint(d[13]), __float_as_uint(d[14]));
            const u32 m5 = umin3(m0, m1, __float_as_uint(d[15]));
            const u32 m6 = umin3(m2, m3, m4);
            bests[f] = umin3(m5, m6, bests[f]);
        }
    }

    #pragma unroll
    for (int f = 0; f < 4; ++f) {
        u32 bu = bests[f];
        const u32 other = __shfl_xor(bu, 32);                 // merge row halves
        bu = bu < other ? bu : other;
        const int q = qw + f * 32 + (lane & 31);
        float v = (__uint_as_float(bu) - 512.0f) + sqq[q];    // un-bias
        v = fmaxf(v, 0.0f);                                   // clamp: keep >= 0
        if (lane < 32) atomicMin(out + q, __float_as_uint(v));
    }
}

// ---------- fallback (round-2 VALU kernel) if ws too small ----------
#define FSLICE 512
#define FROWS  512
__global__ __launch_bounds__(256)
void chamfer_dir_kernel(const float* __restrict__ P, const float* __restrict__ Q,
                        unsigned int* __restrict__ out, int Np, int Mp) {
    __shared__ float4 lds[FSLICE];
    const int tid = threadIdx.x;
    const int rowBase = blockIdx.x * FROWS;
    const int b = rowBase / Np;
    const int slice0 = blockIdx.y * FSLICE;
    const float* qs = Q + ((size_t)b * Mp + slice0) * 3;
    #pragma unroll
    for (int i = tid; i < FSLICE; i += 256) {
        const float x = qs[3*i+0], y = qs[3*i+1], z = qs[3*i+2];
        lds[i] = make_float4(x, y, z, fmaf(x, x, fmaf(y, y, z * z)));
    }
    const int q0 = rowBase + tid, q1 = q0 + 256;
    const float* p0 = P + (size_t)q0 * 3;
    const float* p1 = P + (size_t)q1 * 3;
    const float x0=p0[0], y0=p0[1], z0=p0[2], x1=p1[0], y1=p1[1], z1=p1[2];
    const float m2x0=-2*x0, m2y0=-2*y0, m2z0=-2*z0, m2x1=-2*x1, m2y1=-2*y1, m2z1=-2*z1;
    const float sqp0 = fmaf(x0,x0,fmaf(y0,y0,z0*z0));
    const float sqp1 = fmaf(x1,x1,fmaf(y1,y1,z1*z1));
    __syncthreads();
    float best0 = 3.0e38f, best1 = 3.0e38f;
    #pragma unroll 4
    for (int j = 0; j < FSLICE; j += 2) {
        const float4 a = lds[j], c = lds[j+1];
        const float d00 = fmaf(m2x0,a.x,fmaf(m2y0,a.y,fmaf(m2z0,a.z,a.w)));
        const float d01 = fmaf(m2x0,c.x,fmaf(m2y0,c.y,fmaf(m2z0,c.z,c.w)));
        best0 = fminf(fminf(d00,d01), best0);
        const float d10 = fmaf(m2x1,a.x,fmaf(m2y1,a.y,fmaf(m2z1,a.z,a.w)));
        const float d11 = fmaf(m2x1,c.x,fmaf(m2y1,c.y,fmaf(m2z1,c.z,c.w)));
        best1 = fminf(fminf(d10,d11), best1);
    }
    atomicMin(out + q0, __float_as_uint(fmaxf(best0 + sqp0, 0.f)));
    atomicMin(out + q1, __float_as_uint(fmaxf(best1 + sqp1, 0.f)));
}

extern "C" void kernel_launch(void* const* d_in, const int* in_sizes, int n_in,
                              void* d_out, int out_size, void* d_ws, size_t ws_size,
                              hipStream_t stream) {
    const float* in1 = (const float*)d_in[0];   // [B, N, 3]
    const float* in2 = (const float*)d_in[1];   // [B, M, 3]
    const int B = 8;
    const int N = in_sizes[0] / (B * 3);
    const int M = in_sizes[1] / (B * 3);
    const int P1 = B * N, P2 = B * M;
    unsigned int* out = (unsigned int*)d_out;

    const size_t packBytes1 = (size_t)P1 * 32, packBytes2 = (size_t)P2 * 32;
    const size_t need = 2*packBytes1 + 2*packBytes2 + (size_t)(P1+P2)*4;

    if (ws_size >= need && N == M) {
        char* w = (char*)d_ws;
        ushort* A1 = (ushort*)(w);
        ushort* B1 = (ushort*)(w + packBytes1);
        ushort* A2 = (ushort*)(w + 2*packBytes1);
        ushort* B2 = (ushort*)(w + 2*packBytes1 + packBytes2);
        float*  S1 = (float*) (w + 2*packBytes1 + 2*packBytes2);
        float*  S2 = (float*) (w + 2*packBytes1 + 2*packBytes2 + (size_t)P1*4);

        pack_all_kernel<<<(P1 + P2 + 255)/256, 256, 0, stream>>>(
            in1, in2, A1, B1, S1, A2, B2, S2, out, P1, P2);

        // z=0: dist1 (queries=input1, targets=input2); z=1: dist2
        dim3 g(P1 / QPB, M / TSLICE, 2);
        chamfer_mfma_kernel<<<g, 256, 0, stream>>>(
            A2, B1, S1, out,        // dir 1
            A1, B2, S2, out + P1,   // dir 2
            N, M);
    } else {
        hipMemsetAsync(d_out, 0x7F, (size_t)out_size * sizeof(float), stream);
        dim3 g1(P1 / FROWS, M / FSLICE);
        chamfer_dir_kernel<<<g1, 256, 0, stream>>>(in1, in2, out, N, M);
        dim3 g2(P2 / FROWS, N / FSLICE);
        chamfer_dir_kernel<<<g2, 256, 0, stream>>>(in2, in1, out + P1, M, N);
    }
}

// Round 10
// 50.112 us; speedup vs baseline: 1.5115x; 1.1914x over previous
//
#include <hip/hip_runtime.h>

// Chamfer distance via bf16 split-MFMA.
//   d(p,q') = ||p||^2 + (||q'||^2 + 512 - 2 p.q') - 512
// Rank-15 GEMM in bf16 hi/lo-split form; one v_mfma_f32_32x32x16_bf16 =
// 32 targets x 32 queries = 1024 pairs. +512 bias K-slot keeps all outputs
// positive so the 16->1 fold runs as v_min3_u32 (bit order == float order).
//
// R5-R9 lesson: the MFMA *intrinsic*'s C/D live in AGPRs; the compiler pays
// ~16 v_accvgpr_write (zero-C remat) + 16 v_accvgpr_read (D->fold) per MFMA
// = ~45 extra VALU ops/MFMA (measured 53 total vs 8 fold ops). No indirect
// lever (launch bounds, opaque zero, fold shape) changes the class choice.
// R10 fix: inline-asm MFMA with "v"-class operands (gfx90a+ MFMA reads/
// writes VGPRs directly) -> zero accvgpr traffic. R6 hazard lesson handled
// INSIDE the asm: 5x s_nop 7 (40 cy) after the MFMA pads the MFMA->VALU
// read-of-D hazard before the compiler's folds can touch D.
// __launch_bounds__(256,4): 128-VGPR budget, no spills, 4 waves/SIMD.

typedef __attribute__((ext_vector_type(8))) short  s16x8;
typedef __attribute__((ext_vector_type(16))) float f32x16;
typedef unsigned int u32;

#define TSLICE 512    // targets staged in LDS per block (16 KB packed)
#define QPB    512    // queries per block (4 waves x 128)
#define QPW    128    // queries per wave (4 frags of 32)

__device__ inline u32 umin3(u32 a, u32 b, u32 c) {
    const u32 t = a < b ? a : b;
    return t < c ? t : c;           // -> v_min3_u32
}

// MFMA with VGPR-class C/D + internal hazard padding. "=&v" (early-clobber)
// forbids partial D/C aliasing; the s_nops make D safe for any following
// compiler-emitted VALU read (INLINEASM is invisible to the hazard
// recognizer, so the padding must live inside the block).
__device__ inline f32x16 mfma_vgpr(const s16x8 a, const s16x8 b, const f32x16 c) {
    f32x16 d;
    asm("v_mfma_f32_32x32x16_bf16 %0, %1, %2, %3\n\t"
        "s_nop 7\n\ts_nop 7\n\ts_nop 7\n\ts_nop 7\n\ts_nop 7"
        : "=&v"(d) : "v"(a), "v"(b), "v"(c));
    return d;
}

// ---------- bf16 split helper (bit-level, RNE) ----------
__device__ inline unsigned int bf16bits(float v, float &hival) {
    unsigned int u = __float_as_uint(v);
    unsigned int r = (u + 0x7FFFu + ((u >> 16) & 1u)) >> 16;
    hival = __uint_as_float(r << 16);
    return r;
}

// ---------- fused pre-pass: pack both inputs + sentinel-init d_out ----------
__global__ __launch_bounds__(256)
void pack_all_kernel(const float* __restrict__ in1, const float* __restrict__ in2,
                     ushort* __restrict__ A1, ushort* __restrict__ B1, float* __restrict__ S1,
                     ushort* __restrict__ A2, ushort* __restrict__ B2, float* __restrict__ S2,
                     unsigned int* __restrict__ out, int P1, int P2) {
    const int g = blockIdx.x * 256 + threadIdx.x;
    if (g >= P1 + P2) return;
    out[g] = 0x7F7F7F7Fu;                 // 3.39e38f sentinel (flat over both outs)

    const float* src; ushort* pA; ushort* pB; float* sq; int p;
    if (g < P1) { src = in1; pA = A1; pB = B1; sq = S1; p = g; }
    else        { src = in2; pA = A2; pB = B2; sq = S2; p = g - P1; }

    const float x = src[3*p+0], y = src[3*p+1], z = src[3*p+2];
    float xhf, xlf, yhf, ylf, zhf, zlf, shf, tmp;
    const ushort xh = (ushort)bf16bits(x, xhf);
    const ushort xl = (ushort)bf16bits(x - xhf, xlf);
    const ushort yh = (ushort)bf16bits(y, yhf);
    const ushort yl = (ushort)bf16bits(y - yhf, ylf);
    const ushort zh = (ushort)bf16bits(z, zhf);
    const ushort zl = (ushort)bf16bits(z - zhf, zlf);
    const float s = fmaf(x, x, fmaf(y, y, z * z));
    const ushort sh = (ushort)bf16bits(s, shf);
    const ushort sl = (ushort)bf16bits(s - shf, tmp);
    const ushort m2xh = (ushort)bf16bits(-2.0f * xhf, tmp);
    const ushort m2xl = (ushort)bf16bits(-2.0f * xlf, tmp);
    const ushort m2yh = (ushort)bf16bits(-2.0f * yhf, tmp);
    const ushort m2yl = (ushort)bf16bits(-2.0f * ylf, tmp);
    const ushort m2zh = (ushort)bf16bits(-2.0f * zhf, tmp);
    const ushort m2zl = (ushort)bf16bits(-2.0f * zlf, tmp);
    const ushort ONE  = 0x3F80;           // 1.0 bf16
    const ushort BIAS = 0x4400;           // 512.0 bf16 (exact)

    const s16x8 a0 = {(short)m2xh,(short)m2xl,(short)m2xh,(short)m2xl,
                      (short)m2yh,(short)m2yl,(short)m2yh,(short)m2yl};
    const s16x8 a1 = {(short)m2zh,(short)m2zl,(short)m2zh,(short)m2zl,
                      (short)sh,  (short)sl,  (short)BIAS, 0};
    const s16x8 b0 = {(short)xh,(short)xh,(short)xl,(short)xl,
                      (short)yh,(short)yh,(short)yl,(short)yl};
    const s16x8 b1 = {(short)zh,(short)zh,(short)zl,(short)zl,
                      (short)ONE,(short)ONE,(short)ONE, 0};

    s16x8* A8 = (s16x8*)pA;
    s16x8* B8 = (s16x8*)pB;
    // A: fragment-linear per 32-target tile: chunk = tilebase*64 + khalf*32 + row
    const int c0 = (p & ~31) * 2 + (p & 31);
    A8[c0]      = a0;   // k-slots 0-7  (lanes 0-31)
    A8[c0 + 32] = a1;   // k-slots 8-15 (lanes 32-63)
    // B: point-major
    B8[2*p]     = b0;
    B8[2*p + 1] = b1;
    sq[p] = s;
}

// ---------- main MFMA kernel, both directions (blockIdx.z selects) ----------
__global__ __launch_bounds__(256, 4)
void chamfer_mfma_kernel(const ushort* __restrict__ Ad1, const ushort* __restrict__ Bd1,
                         const float*  __restrict__ Sd1, unsigned int* __restrict__ Od1,
                         const ushort* __restrict__ Ad2, const ushort* __restrict__ Bd2,
                         const float*  __restrict__ Sd2, unsigned int* __restrict__ Od2,
                         int Np, int Mp) {
    __shared__ s16x8 lds8[TSLICE * 2];   // 16 KB
    const int z = blockIdx.z;
    const ushort* pA  = z ? Ad2 : Ad1;
    const ushort* pB  = z ? Bd2 : Bd1;
    const float*  sqq = z ? Sd2 : Sd1;
    unsigned int* out = z ? Od2 : Od1;

    const int tid  = threadIdx.x;
    const int lane = tid & 63;
    const int wid  = tid >> 6;
    const int qblock = blockIdx.x * QPB;        // flat over B*Np (QPB | Np)
    const int b = qblock / Np;
    const size_t gchunk = ((size_t)b * Mp + (size_t)blockIdx.y * TSLICE) * 2;
    const s16x8* gA = (const s16x8*)pA + gchunk;
    for (int i = tid; i < TSLICE * 2; i += 256) lds8[i] = gA[i];

    // B fragments: 4 x 32 queries, loop-invariant in registers
    const int qw = qblock + wid * QPW;
    s16x8 bfr[4];
    #pragma unroll
    for (int f = 0; f < 4; ++f) {
        const int q = qw + f * 32 + (lane & 31);
        bfr[f] = *(const s16x8*)(pB + (size_t)q * 16 + (size_t)(lane >> 5) * 8);
    }
    __syncthreads();

    f32x16 cz = {0.f,0.f,0.f,0.f,0.f,0.f,0.f,0.f,
                 0.f,0.f,0.f,0.f,0.f,0.f,0.f,0.f};
    // Pin cz as a live VGPR tuple (prevents per-iteration remat).
    asm("" : "+v"(cz));

    u32 bests[4] = {0x7F7F7F7Fu, 0x7F7F7F7Fu, 0x7F7F7F7Fu, 0x7F7F7F7Fu};

    const int NT = TSLICE / 32;
    for (int t = 0; t < NT; ++t) {
        const s16x8 a = lds8[t * 64 + lane];
        #pragma unroll
        for (int f = 0; f < 4; ++f) {
            const f32x16 d = mfma_vgpr(a, bfr[f], cz);
            // all outputs > 0 (bias) -> uint bit order == float order.
            // 16 -> 1 in 8 v_min3_u32.
            const u32 m0 = umin3(__float_as_uint(d[0]),  __float_as_uint(d[1]),  __float_as_uint(d[2]));
            const u32 m1 = umin3(__float_as_uint(d[3]),  __float_as_uint(d[4]),  __float_as_uint(d[5]));
            const u32 m2 = umin3(__float_as_uint(d[6]),  __float_as_uint(d[7]),  __float_as_uint(d[8]));
            const u32 m3 = umin3(__float_as_uint(d[9]),  __float_as_uint(d[10]), __float_as_uint(d[11]));
            const u32 m4 = umin3(__float_as_uint(d[12]), __float_as_uint(d[13]), __float_as_uint(d[14]));
            const u32 m5 = umin3(m0, m1, __float_as_uint(d[15]));
            const u32 m6 = umin3(m2, m3, m4);
            bests[f] = umin3(m5, m6, bests[f]);
        }
    }

    #pragma unroll
    for (int f = 0; f < 4; ++f) {
        u32 bu = bests[f];
        const u32 other = __shfl_xor(bu, 32);                 // merge row halves
        bu = bu < other ? bu : other;
        const int q = qw + f * 32 + (lane & 31);
        float v = (__uint_as_float(bu) - 512.0f) + sqq[q];    // un-bias
        v = fmaxf(v, 0.0f);                                   // clamp: keep >= 0
        if (lane < 32) atomicMin(out + q, __float_as_uint(v));
    }
}

// ---------- fallback (round-2 VALU kernel) if ws too small ----------
#define FSLICE 512
#define FROWS  512
__global__ __launch_bounds__(256)
void chamfer_dir_kernel(const float* __restrict__ P, const float* __restrict__ Q,
                        unsigned int* __restrict__ out, int Np, int Mp) {
    __shared__ float4 lds[FSLICE];
    const int tid = threadIdx.x;
    const int rowBase = blockIdx.x * FROWS;
    const int b = rowBase / Np;
    const int slice0 = blockIdx.y * FSLICE;
    const float* qs = Q + ((size_t)b * Mp + slice0) * 3;
    #pragma unroll
    for (int i = tid; i < FSLICE; i += 256) {
        const float x = qs[3*i+0], y = qs[3*i+1], z = qs[3*i+2];
        lds[i] = make_float4(x, y, z, fmaf(x, x, fmaf(y, y, z * z)));
    }
    const int q0 = rowBase + tid, q1 = q0 + 256;
    const float* p0 = P + (size_t)q0 * 3;
    const float* p1 = P + (size_t)q1 * 3;
    const float x0=p0[0], y0=p0[1], z0=p0[2], x1=p1[0], y1=p1[1], z1=p1[2];
    const float m2x0=-2*x0, m2y0=-2*y0, m2z0=-2*z0, m2x1=-2*x1, m2y1=-2*y1, m2z1=-2*z1;
    const float sqp0 = fmaf(x0,x0,fmaf(y0,y0,z0*z0));
    const float sqp1 = fmaf(x1,x1,fmaf(y1,y1,z1*z1));
    __syncthreads();
    float best0 = 3.0e38f, best1 = 3.0e38f;
    #pragma unroll 4
    for (int j = 0; j < FSLICE; j += 2) {
        const float4 a = lds[j], c = lds[j+1];
        const float d00 = fmaf(m2x0,a.x,fmaf(m2y0,a.y,fmaf(m2z0,a.z,a.w)));
        const float d01 = fmaf(m2x0,c.x,fmaf(m2y0,c.y,fmaf(m2z0,c.z,c.w)));
        best0 = fminf(fminf(d00,d01), best0);
        const float d10 = fmaf(m2x1,a.x,fmaf(m2y1,a.y,fmaf(m2z1,a.z,a.w)));
        const float d11 = fmaf(m2x1,c.x,fmaf(m2y1,c.y,fmaf(m2z1,c.z,c.w)));
        best1 = fminf(fminf(d10,d11), best1);
    }
    atomicMin(out + q0, __float_as_uint(fmaxf(best0 + sqp0, 0.f)));
    atomicMin(out + q1, __float_as_uint(fmaxf(best1 + sqp1, 0.f)));
}

extern "C" void kernel_launch(void* const* d_in, const int* in_sizes, int n_in,
                              void* d_out, int out_size, void* d_ws, size_t ws_size,
                              hipStream_t stream) {
    const float* in1 = (const float*)d_in[0];   // [B, N, 3]
    const float* in2 = (const float*)d_in[1];   // [B, M, 3]
    const int B = 8;
    const int N = in_sizes[0] / (B * 3);
    const int M = in_sizes[1] / (B * 3);
    const int P1 = B * N, P2 = B * M;
    unsigned int* out = (unsigned int*)d_out;

    const size_t packBytes1 = (size_t)P1 * 32, packBytes2 = (size_t)P2 * 32;
    const size_t need = 2*packBytes1 + 2*packBytes2 + (size_t)(P1+P2)*4;

    if (ws_size >= need && N == M) {
        char* w = (char*)d_ws;
        ushort* A1 = (ushort*)(w);
        ushort* B1 = (ushort*)(w + packBytes1);
        ushort* A2 = (ushort*)(w + 2*packBytes1);
        ushort* B2 = (ushort*)(w + 2*packBytes1 + packBytes2);
        float*  S1 = (float*) (w + 2*packBytes1 + 2*packBytes2);
        float*  S2 = (float*) (w + 2*packBytes1 + 2*packBytes2 + (size_t)P1*4);

        pack_all_kernel<<<(P1 + P2 + 255)/256, 256, 0, stream>>>(
            in1, in2, A1, B1, S1, A2, B2, S2, out, P1, P2);

        // z=0: dist1 (queries=input1, targets=input2); z=1: dist2
        dim3 g(P1 / QPB, M / TSLICE, 2);
        chamfer_mfma_kernel<<<g, 256, 0, stream>>>(
            A2, B1, S1, out,        // dir 1
            A1, B2, S2, out + P1,   // dir 2
            N, M);
    } else {
        hipMemsetAsync(d_out, 0x7F, (size_t)out_size * sizeof(float), stream);
        dim3 g1(P1 / FROWS, M / FSLICE);
        chamfer_dir_kernel<<<g1, 256, 0, stream>>>(in1, in2, out, N, M);
        dim3 g2(P2 / FROWS, N / FSLICE);
        chamfer_dir_kernel<<<g2, 256, 0, stream>>>(in2, in1, out + P1, M, N);
    }
}

// Round 11
// 50.020 us; speedup vs baseline: 1.5143x; 1.0018x over previous
//
#include <hip/hip_runtime.h>

// Chamfer distance via bf16 split-MFMA.
//   d(p,q') = ||p||^2 + (||q'||^2 + 512 - 2 p.q') - 512
// Rank-15 GEMM in bf16 hi/lo-split form; one v_mfma_f32_32x32x16_bf16 =
// 32 targets x 32 queries = 1024 pairs. +512 bias K-slot keeps all outputs
// positive so the 16->1 fold runs as v_min3_u32 (bit order == float order).
//
// R5-R9: intrinsic keeps C/D in AGPRs -> ~32 accvgpr copies/MFMA. R10:
// inline-asm MFMA with "v"-class C/D killed the zero-C remat (-10us) but
// stayed 3x the 13.6us MFMA floor: the 4 independent "=&v" asm blocks get
// hoisted together -> 4 live D tuples (64 VGPR) -> spill at the 128 cap.
// R11: (1) chain-serialize -- previous frag's bests is a "+v" inout of the
// next MFMA asm (untouched by hw, value preserved) so exactly one D tuple
// is live; (2) nops 40->24cy (req is 18 for 16-pass MFMA D->VALU read);
// (3) prefetch next A fragment before folding (hide ~120cy LDS latency).

typedef __attribute__((ext_vector_type(8))) short  s16x8;
typedef __attribute__((ext_vector_type(16))) float f32x16;
typedef unsigned int u32;

#define TSLICE 512    // targets staged in LDS per block (16 KB packed)
#define QPB    512    // queries per block (4 waves x 128)
#define QPW    128    // queries per wave (4 frags of 32)

__device__ inline u32 umin3(u32 a, u32 b, u32 c) {
    const u32 t = a < b ? a : b;
    return t < c ? t : c;           // -> v_min3_u32
}

// MFMA with VGPR-class C/D + internal hazard padding (24 cy > 18 required
// for VALU read of 16-pass MFMA D; INLINEASM is invisible to the hazard
// recognizer so padding lives inside). `chain` ("+v") is untouched by the
// asm text -- it only creates a scheduling dependency so MFMA(f+1) cannot
// hoist above fold(f); this caps live D tuples at one (VGPR fit, no spill).
__device__ inline f32x16 mfma_chain(const s16x8 a, const s16x8 b,
                                    const f32x16 c, u32& chain) {
    f32x16 d;
    asm("v_mfma_f32_32x32x16_bf16 %0, %2, %3, %4\n\t"
        "s_nop 7\n\ts_nop 7\n\ts_nop 7"
        : "=&v"(d), "+v"(chain) : "v"(a), "v"(b), "v"(c));
    return d;
}

// ---------- bf16 split helper (bit-level, RNE) ----------
__device__ inline unsigned int bf16bits(float v, float &hival) {
    unsigned int u = __float_as_uint(v);
    unsigned int r = (u + 0x7FFFu + ((u >> 16) & 1u)) >> 16;
    hival = __uint_as_float(r << 16);
    return r;
}

// ---------- fused pre-pass: pack both inputs + sentinel-init d_out ----------
__global__ __launch_bounds__(256)
void pack_all_kernel(const float* __restrict__ in1, const float* __restrict__ in2,
                     ushort* __restrict__ A1, ushort* __restrict__ B1, float* __restrict__ S1,
                     ushort* __restrict__ A2, ushort* __restrict__ B2, float* __restrict__ S2,
                     unsigned int* __restrict__ out, int P1, int P2) {
    const int g = blockIdx.x * 256 + threadIdx.x;
    if (g >= P1 + P2) return;
    out[g] = 0x7F7F7F7Fu;                 // 3.39e38f sentinel (flat over both outs)

    const float* src; ushort* pA; ushort* pB; float* sq; int p;
    if (g < P1) { src = in1; pA = A1; pB = B1; sq = S1; p = g; }
    else        { src = in2; pA = A2; pB = B2; sq = S2; p = g - P1; }

    const float x = src[3*p+0], y = src[3*p+1], z = src[3*p+2];
    float xhf, xlf, yhf, ylf, zhf, zlf, shf, tmp;
    const ushort xh = (ushort)bf16bits(x, xhf);
    const ushort xl = (ushort)bf16bits(x - xhf, xlf);
    const ushort yh = (ushort)bf16bits(y, yhf);
    const ushort yl = (ushort)bf16bits(y - yhf, ylf);
    const ushort zh = (ushort)bf16bits(z, zhf);
    const ushort zl = (ushort)bf16bits(z - zhf, zlf);
    const float s = fmaf(x, x, fmaf(y, y, z * z));
    const ushort sh = (ushort)bf16bits(s, shf);
    const ushort sl = (ushort)bf16bits(s - shf, tmp);
    const ushort m2xh = (ushort)bf16bits(-2.0f * xhf, tmp);
    const ushort m2xl = (ushort)bf16bits(-2.0f * xlf, tmp);
    const ushort m2yh = (ushort)bf16bits(-2.0f * yhf, tmp);
    const ushort m2yl = (ushort)bf16bits(-2.0f * ylf, tmp);
    const ushort m2zh = (ushort)bf16bits(-2.0f * zhf, tmp);
    const ushort m2zl = (ushort)bf16bits(-2.0f * zlf, tmp);
    const ushort ONE  = 0x3F80;           // 1.0 bf16
    const ushort BIAS = 0x4400;           // 512.0 bf16 (exact)

    const s16x8 a0 = {(short)m2xh,(short)m2xl,(short)m2xh,(short)m2xl,
                      (short)m2yh,(short)m2yl,(short)m2yh,(short)m2yl};
    const s16x8 a1 = {(short)m2zh,(short)m2zl,(short)m2zh,(short)m2zl,
                      (short)sh,  (short)sl,  (short)BIAS, 0};
    const s16x8 b0 = {(short)xh,(short)xh,(short)xl,(short)xl,
                      (short)yh,(short)yh,(short)yl,(short)yl};
    const s16x8 b1 = {(short)zh,(short)zh,(short)zl,(short)zl,
                      (short)ONE,(short)ONE,(short)ONE, 0};

    s16x8* A8 = (s16x8*)pA;
    s16x8* B8 = (s16x8*)pB;
    // A: fragment-linear per 32-target tile: chunk = tilebase*64 + khalf*32 + row
    const int c0 = (p & ~31) * 2 + (p & 31);
    A8[c0]      = a0;   // k-slots 0-7  (lanes 0-31)
    A8[c0 + 32] = a1;   // k-slots 8-15 (lanes 32-63)
    // B: point-major
    B8[2*p]     = b0;
    B8[2*p + 1] = b1;
    sq[p] = s;
}

// ---------- main MFMA kernel, both directions (blockIdx.z selects) ----------
__global__ __launch_bounds__(256, 4)
void chamfer_mfma_kernel(const ushort* __restrict__ Ad1, const ushort* __restrict__ Bd1,
                         const float*  __restrict__ Sd1, unsigned int* __restrict__ Od1,
                         const ushort* __restrict__ Ad2, const ushort* __restrict__ Bd2,
                         const float*  __restrict__ Sd2, unsigned int* __restrict__ Od2,
                         int Np, int Mp) {
    __shared__ s16x8 lds8[TSLICE * 2];   // 16 KB
    const int z = blockIdx.z;
    const ushort* pA  = z ? Ad2 : Ad1;
    const ushort* pB  = z ? Bd2 : Bd1;
    const float*  sqq = z ? Sd2 : Sd1;
    unsigned int* out = z ? Od2 : Od1;

    const int tid  = threadIdx.x;
    const int lane = tid & 63;
    const int wid  = tid >> 6;
    const int qblock = blockIdx.x * QPB;        // flat over B*Np (QPB | Np)
    const int b = qblock / Np;
    const size_t gchunk = ((size_t)b * Mp + (size_t)blockIdx.y * TSLICE) * 2;
    const s16x8* gA = (const s16x8*)pA + gchunk;
    for (int i = tid; i < TSLICE * 2; i += 256) lds8[i] = gA[i];

    // B fragments: 4 x 32 queries, loop-invariant in registers
    const int qw = qblock + wid * QPW;
    s16x8 bfr[4];
    #pragma unroll
    for (int f = 0; f < 4; ++f) {
        const int q = qw + f * 32 + (lane & 31);
        bfr[f] = *(const s16x8*)(pB + (size_t)q * 16 + (size_t)(lane >> 5) * 8);
    }
    __syncthreads();

    f32x16 cz = {0.f,0.f,0.f,0.f,0.f,0.f,0.f,0.f,
                 0.f,0.f,0.f,0.f,0.f,0.f,0.f,0.f};
    // Pin cz as a live VGPR tuple (prevents per-iteration remat).
    asm("" : "+v"(cz));

    u32 bests[4] = {0x7F7F7F7Fu, 0x7F7F7F7Fu, 0x7F7F7F7Fu, 0x7F7F7F7Fu};

    const int NT = TSLICE / 32;
    s16x8 a = lds8[lane];
    for (int t = 0; t < NT; ++t) {
        const int tn = (t + 1 < NT) ? (t + 1) : t;
        const s16x8 an = lds8[tn * 64 + lane];   // prefetch next A fragment
        #pragma unroll
        for (int f = 0; f < 4; ++f) {
            // chain = previous frag's bests: orders fold(f-1) before MFMA(f)
            const f32x16 d = mfma_chain(a, bfr[f], cz, bests[(f + 3) & 3]);
            // all outputs > 0 (bias) -> uint bit order == float order.
            const u32 m0 = umin3(__float_as_uint(d[0]),  __float_as_uint(d[1]),  __float_as_uint(d[2]));
            const u32 m1 = umin3(__float_as_uint(d[3]),  __float_as_uint(d[4]),  __float_as_uint(d[5]));
            const u32 m2 = umin3(__float_as_uint(d[6]),  __float_as_uint(d[7]),  __float_as_uint(d[8]));
            const u32 m3 = umin3(__float_as_uint(d[9]),  __float_as_uint(d[10]), __float_as_uint(d[11]));
            const u32 m4 = umin3(__float_as_uint(d[12]), __float_as_uint(d[13]), __float_as_uint(d[14]));
            const u32 m5 = umin3(m0, m1, __float_as_uint(d[15]));
            const u32 m6 = umin3(m2, m3, m4);
            bests[f] = umin3(m5, m6, bests[f]);
        }
        a = an;
    }

    #pragma unroll
    for (int f = 0; f < 4; ++f) {
        u32 bu = bests[f];
        const u32 other = __shfl_xor(bu, 32);                 // merge row halves
        bu = bu < other ? bu : other;
        const int q = qw + f * 32 + (lane & 31);
        float v = (__uint_as_float(bu) - 512.0f) + sqq[q];    // un-bias
        v = fmaxf(v, 0.0f);                                   // clamp: keep >= 0
        if (lane < 32) atomicMin(out + q, __float_as_uint(v));
    }
}

// ---------- fallback (round-2 VALU kernel) if ws too small ----------
#define FSLICE 512
#define FROWS  512
__global__ __launch_bounds__(256)
void chamfer_dir_kernel(const float* __restrict__ P, const float* __restrict__ Q,
                        unsigned int* __restrict__ out, int Np, int Mp) {
    __shared__ float4 lds[FSLICE];
    const int tid = threadIdx.x;
    const int rowBase = blockIdx.x * FROWS;
    const int b = rowBase / Np;
    const int slice0 = blockIdx.y * FSLICE;
    const float* qs = Q + ((size_t)b * Mp + slice0) * 3;
    #pragma unroll
    for (int i = tid; i < FSLICE; i += 256) {
        const float x = qs[3*i+0], y = qs[3*i+1], z = qs[3*i+2];
        lds[i] = make_float4(x, y, z, fmaf(x, x, fmaf(y, y, z * z)));
    }
    const int q0 = rowBase + tid, q1 = q0 + 256;
    const float* p0 = P + (size_t)q0 * 3;
    const float* p1 = P + (size_t)q1 * 3;
    const float x0=p0[0], y0=p0[1], z0=p0[2], x1=p1[0], y1=p1[1], z1=p1[2];
    const float m2x0=-2*x0, m2y0=-2*y0, m2z0=-2*z0, m2x1=-2*x1, m2y1=-2*y1, m2z1=-2*z1;
    const float sqp0 = fmaf(x0,x0,fmaf(y0,y0,z0*z0));
    const float sqp1 = fmaf(x1,x1,fmaf(y1,y1,z1*z1));
    __syncthreads();
    float best0 = 3.0e38f, best1 = 3.0e38f;
    #pragma unroll 4
    for (int j = 0; j < FSLICE; j += 2) {
        const float4 a = lds[j], c = lds[j+1];
        const float d00 = fmaf(m2x0,a.x,fmaf(m2y0,a.y,fmaf(m2z0,a.z,a.w)));
        const float d01 = fmaf(m2x0,c.x,fmaf(m2y0,c.y,fmaf(m2z0,c.z,c.w)));
        best0 = fminf(fminf(d00,d01), best0);
        const float d10 = fmaf(m2x1,a.x,fmaf(m2y1,a.y,fmaf(m2z1,a.z,a.w)));
        const float d11 = fmaf(m2x1,c.x,fmaf(m2y1,c.y,fmaf(m2z1,c.z,c.w)));
        best1 = fminf(fminf(d10,d11), best1);
    }
    atomicMin(out + q0, __float_as_uint(fmaxf(best0 + sqp0, 0.f)));
    atomicMin(out + q1, __float_as_uint(fmaxf(best1 + sqp1, 0.f)));
}

extern "C" void kernel_launch(void* const* d_in, const int* in_sizes, int n_in,
                              void* d_out, int out_size, void* d_ws, size_t ws_size,
                              hipStream_t stream) {
    const float* in1 = (const float*)d_in[0];   // [B, N, 3]
    const float* in2 = (const float*)d_in[1];   // [B, M, 3]
    const int B = 8;
    const int N = in_sizes[0] / (B * 3);
    const int M = in_sizes[1] / (B * 3);
    const int P1 = B * N, P2 = B * M;
    unsigned int* out = (unsigned int*)d_out;

    const size_t packBytes1 = (size_t)P1 * 32, packBytes2 = (size_t)P2 * 32;
    const size_t need = 2*packBytes1 + 2*packBytes2 + (size_t)(P1+P2)*4;

    if (ws_size >= need && N == M) {
        char* w = (char*)d_ws;
        ushort* A1 = (ushort*)(w);
        ushort* B1 = (ushort*)(w + packBytes1);
        ushort* A2 = (ushort*)(w + 2*packBytes1);
        ushort* B2 = (ushort*)(w + 2*packBytes1 + packBytes2);
        float*  S1 = (float*) (w + 2*packBytes1 + 2*packBytes2);
        float*  S2 = (float*) (w + 2*packBytes1 + 2*packBytes2 + (size_t)P1*4);

        pack_all_kernel<<<(P1 + P2 + 255)/256, 256, 0, stream>>>(
            in1, in2, A1, B1, S1, A2, B2, S2, out, P1, P2);

        // z=0: dist1 (queries=input1, targets=input2); z=1: dist2
        dim3 g(P1 / QPB, M / TSLICE, 2);
        chamfer_mfma_kernel<<<g, 256, 0, stream>>>(
            A2, B1, S1, out,        // dir 1
            A1, B2, S2, out + P1,   // dir 2
            N, M);
    } else {
        hipMemsetAsync(d_out, 0x7F, (size_t)out_size * sizeof(float), stream);
        dim3 g1(P1 / FROWS, M / FSLICE);
        chamfer_dir_kernel<<<g1, 256, 0, stream>>>(in1, in2, out, N, M);
        dim3 g2(P2 / FROWS, N / FSLICE);
        chamfer_dir_kernel<<<g2, 256, 0, stream>>>(in2, in1, out + P1, M, N);
    }
}

// Round 12
// 49.149 us; speedup vs baseline: 1.5411x; 1.0177x over previous
//
#include <hip/hip_runtime.h>

// Chamfer distance via bf16 split-MFMA.
//   d(p,q') = ||p||^2 + (||q'||^2 + 512 - 2 p.q') - 512
// Rank-15 GEMM in bf16 hi/lo-split form; one v_mfma_f32_32x32x16_bf16 =
// 32 targets x 32 queries = 1024 pairs. +512 bias K-slot keeps outputs
// positive so the 16->1 fold runs as v_min3_u32 (bit order == float order).
//
// R5-R9: intrinsic keeps C/D in AGPRs -> ~32 accvgpr copies/MFMA (VALU-pipe
// bound, 43us). R10/R11: asm MFMA with VGPR C/D + 24cy in-asm nops + separate
// fold -> per-wave serial chain ~47cy/MFMA; with ~1 wave/SIMD resident the
// chain is fully exposed (~42us). In-asm s_nops are a hard serial cost:
// nothing can be scheduled into an asm block.
// R12: fuse MFMA(f) + fold of D(f-1) into ONE asm block. The fold executes
// in the MFMA's shadow; the MFMA->VALU-read-of-D hazard (>=18cy) is met by
// construction: D(f) is first read in block f+1 after 8 min3 (16cy) +
// s_nop 7 (8cy) + issue. "=&v" early-clobbers prevent D/temp aliasing with
// the p-inputs (R6 corruption class). Per-wave cost ~27-30cy/MFMA < 32cy
// pipe period -> matrix-bound even at 1 wave/SIMD.

typedef __attribute__((ext_vector_type(8))) short  s16x8;
typedef __attribute__((ext_vector_type(16))) float f32x16;
typedef unsigned int u32;

#define TSLICE 512    // targets staged in LDS per block (16 KB packed)
#define QPB    512    // queries per block (4 waves x 128)
#define QPW    128    // queries per wave (4 frags of 32)

__device__ inline u32 umin3(u32 a, u32 b, u32 c) {
    const u32 t = a < b ? a : b;
    return t < c ? t : c;           // -> v_min3_u32
}

// One fused step: issue MFMA into a fresh D tuple, then fold the PREVIOUS
// D (p[0..15], >=26cy old by construction) into `best` with 8 v_min3_u32.
// Trailing s_nop 7 pads the gap for the NEXT block's first read of our D.
__device__ inline f32x16 mfma_fold(const s16x8 a, const s16x8 b, const f32x16 c,
                                   const f32x16 p, u32& best) {
    f32x16 d;
    u32 t0, t1, t2, t3, t4;
    asm("v_mfma_f32_32x32x16_bf16 %0, %7, %8, %9\n\t"
        "v_min3_u32 %2, %10, %11, %12\n\t"
        "v_min3_u32 %3, %13, %14, %15\n\t"
        "v_min3_u32 %4, %16, %17, %18\n\t"
        "v_min3_u32 %5, %19, %20, %21\n\t"
        "v_min3_u32 %6, %22, %23, %24\n\t"
        "v_min3_u32 %2, %2, %3, %25\n\t"
        "v_min3_u32 %4, %4, %5, %6\n\t"
        "v_min3_u32 %1, %2, %4, %1\n\t"
        "s_nop 7"
        : "=&v"(d), "+v"(best),
          "=&v"(t0), "=&v"(t1), "=&v"(t2), "=&v"(t3), "=&v"(t4)
        : "v"(a), "v"(b), "v"(c),
          "v"(p[0]),  "v"(p[1]),  "v"(p[2]),  "v"(p[3]),
          "v"(p[4]),  "v"(p[5]),  "v"(p[6]),  "v"(p[7]),
          "v"(p[8]),  "v"(p[9]),  "v"(p[10]), "v"(p[11]),
          "v"(p[12]), "v"(p[13]), "v"(p[14]), "v"(p[15]));
    return d;
}

// ---------- bf16 split helper (bit-level, RNE) ----------
__device__ inline unsigned int bf16bits(float v, float &hival) {
    unsigned int u = __float_as_uint(v);
    unsigned int r = (u + 0x7FFFu + ((u >> 16) & 1u)) >> 16;
    hival = __uint_as_float(r << 16);
    return r;
}

// ---------- fused pre-pass: pack both inputs + sentinel-init d_out ----------
__global__ __launch_bounds__(256)
void pack_all_kernel(const float* __restrict__ in1, const float* __restrict__ in2,
                     ushort* __restrict__ A1, ushort* __restrict__ B1, float* __restrict__ S1,
                     ushort* __restrict__ A2, ushort* __restrict__ B2, float* __restrict__ S2,
                     unsigned int* __restrict__ out, int P1, int P2) {
    const int g = blockIdx.x * 256 + threadIdx.x;
    if (g >= P1 + P2) return;
    out[g] = 0x7F7F7F7Fu;                 // 3.39e38f sentinel (flat over both outs)

    const float* src; ushort* pA; ushort* pB; float* sq; int p;
    if (g < P1) { src = in1; pA = A1; pB = B1; sq = S1; p = g; }
    else        { src = in2; pA = A2; pB = B2; sq = S2; p = g - P1; }

    const float x = src[3*p+0], y = src[3*p+1], z = src[3*p+2];
    float xhf, xlf, yhf, ylf, zhf, zlf, shf, tmp;
    const ushort xh = (ushort)bf16bits(x, xhf);
    const ushort xl = (ushort)bf16bits(x - xhf, xlf);
    const ushort yh = (ushort)bf16bits(y, yhf);
    const ushort yl = (ushort)bf16bits(y - yhf, ylf);
    const ushort zh = (ushort)bf16bits(z, zhf);
    const ushort zl = (ushort)bf16bits(z - zhf, zlf);
    const float s = fmaf(x, x, fmaf(y, y, z * z));
    const ushort sh = (ushort)bf16bits(s, shf);
    const ushort sl = (ushort)bf16bits(s - shf, tmp);
    const ushort m2xh = (ushort)bf16bits(-2.0f * xhf, tmp);
    const ushort m2xl = (ushort)bf16bits(-2.0f * xlf, tmp);
    const ushort m2yh = (ushort)bf16bits(-2.0f * yhf, tmp);
    const ushort m2yl = (ushort)bf16bits(-2.0f * ylf, tmp);
    const ushort m2zh = (ushort)bf16bits(-2.0f * zhf, tmp);
    const ushort m2zl = (ushort)bf16bits(-2.0f * zlf, tmp);
    const ushort ONE  = 0x3F80;           // 1.0 bf16
    const ushort BIAS = 0x4400;           // 512.0 bf16 (exact)

    const s16x8 a0 = {(short)m2xh,(short)m2xl,(short)m2xh,(short)m2xl,
                      (short)m2yh,(short)m2yl,(short)m2yh,(short)m2yl};
    const s16x8 a1 = {(short)m2zh,(short)m2zl,(short)m2zh,(short)m2zl,
                      (short)sh,  (short)sl,  (short)BIAS, 0};
    const s16x8 b0 = {(short)xh,(short)xh,(short)xl,(short)xl,
                      (short)yh,(short)yh,(short)yl,(short)yl};
    const s16x8 b1 = {(short)zh,(short)zh,(short)zl,(short)zl,
                      (short)ONE,(short)ONE,(short)ONE, 0};

    s16x8* A8 = (s16x8*)pA;
    s16x8* B8 = (s16x8*)pB;
    // A: fragment-linear per 32-target tile: chunk = tilebase*64 + khalf*32 + row
    const int c0 = (p & ~31) * 2 + (p & 31);
    A8[c0]      = a0;   // k-slots 0-7  (lanes 0-31)
    A8[c0 + 32] = a1;   // k-slots 8-15 (lanes 32-63)
    // B: point-major
    B8[2*p]     = b0;
    B8[2*p + 1] = b1;
    sq[p] = s;
}

// ---------- main MFMA kernel, both directions (blockIdx.z selects) ----------
__global__ __launch_bounds__(256)
void chamfer_mfma_kernel(const ushort* __restrict__ Ad1, const ushort* __restrict__ Bd1,
                         const float*  __restrict__ Sd1, unsigned int* __restrict__ Od1,
                         const ushort* __restrict__ Ad2, const ushort* __restrict__ Bd2,
                         const float*  __restrict__ Sd2, unsigned int* __restrict__ Od2,
                         int Np, int Mp) {
    __shared__ s16x8 lds8[TSLICE * 2];   // 16 KB
    const int z = blockIdx.z;
    const ushort* pA  = z ? Ad2 : Ad1;
    const ushort* pB  = z ? Bd2 : Bd1;
    const float*  sqq = z ? Sd2 : Sd1;
    unsigned int* out = z ? Od2 : Od1;

    const int tid  = threadIdx.x;
    const int lane = tid & 63;
    const int wid  = tid >> 6;
    const int qblock = blockIdx.x * QPB;        // flat over B*Np (QPB | Np)
    const int b = qblock / Np;
    const size_t gchunk = ((size_t)b * Mp + (size_t)blockIdx.y * TSLICE) * 2;
    const s16x8* gA = (const s16x8*)pA + gchunk;
    for (int i = tid; i < TSLICE * 2; i += 256) lds8[i] = gA[i];

    // B fragments: 4 x 32 queries, loop-invariant in registers
    const int qw = qblock + wid * QPW;
    s16x8 bfr[4];
    #pragma unroll
    for (int f = 0; f < 4; ++f) {
        const int q = qw + f * 32 + (lane & 31);
        bfr[f] = *(const s16x8*)(pB + (size_t)q * 16 + (size_t)(lane >> 5) * 8);
    }
    __syncthreads();

    f32x16 cz = {0.f,0.f,0.f,0.f,0.f,0.f,0.f,0.f,
                 0.f,0.f,0.f,0.f,0.f,0.f,0.f,0.f};
    asm("" : "+v"(cz));   // pin as live VGPR tuple (no per-iter remat)

    u32 bests[4] = {0x7F7F7F7Fu, 0x7F7F7F7Fu, 0x7F7F7F7Fu, 0x7F7F7F7Fu};

    // dprev starts as sentinel: folding it is harmless.
    const float SENT = __uint_as_float(0x7F7F7F7Fu);
    f32x16 dprev = {SENT,SENT,SENT,SENT,SENT,SENT,SENT,SENT,
                    SENT,SENT,SENT,SENT,SENT,SENT,SENT,SENT};

    const int NT = TSLICE / 32;
    s16x8 a = lds8[lane];
    for (int t = 0; t < NT; ++t) {
        const int tn = (t + 1 < NT) ? (t + 1) : t;
        const s16x8 an = lds8[tn * 64 + lane];   // prefetch next A fragment
        // block f folds D(f-1) -> bests[(f+3)&3]
        dprev = mfma_fold(a, bfr[0], cz, dprev, bests[3]);
        dprev = mfma_fold(a, bfr[1], cz, dprev, bests[0]);
        dprev = mfma_fold(a, bfr[2], cz, dprev, bests[1]);
        dprev = mfma_fold(a, bfr[3], cz, dprev, bests[2]);
        a = an;
    }

    // Hazard guard before plain-C reads of the last D (24 cy).
    asm("s_nop 7\n\ts_nop 7\n\ts_nop 7" : "+v"(dprev));
    {   // fold the final tile (belongs to frag 3)
        const u32 m0 = umin3(__float_as_uint(dprev[0]),  __float_as_uint(dprev[1]),  __float_as_uint(dprev[2]));
        const u32 m1 = umin3(__float_as_uint(dprev[3]),  __float_as_uint(dprev[4]),  __float_as_uint(dprev[5]));
        const u32 m2 = umin3(__float_as_uint(dprev[6]),  __float_as_uint(dprev[7]),  __float_as_uint(dprev[8]));
        const u32 m3 = umin3(__float_as_uint(dprev[9]),  __float_as_uint(dprev[10]), __float_as_uint(dprev[11]));
        const u32 m4 = umin3(__float_as_uint(dprev[12]), __float_as_uint(dprev[13]), __float_as_uint(dprev[14]));
        const u32 m5 = umin3(m0, m1, __float_as_uint(dprev[15]));
        const u32 m6 = umin3(m2, m3, m4);
        bests[3] = umin3(m5, m6, bests[3]);
    }

    #pragma unroll
    for (int f = 0; f < 4; ++f) {
        u32 bu = bests[f];
        const u32 other = __shfl_xor(bu, 32);                 // merge row halves
        bu = bu < other ? bu : other;
        const int q = qw + f * 32 + (lane & 31);
        float v = (__uint_as_float(bu) - 512.0f) + sqq[q];    // un-bias
        v = fmaxf(v, 0.0f);                                   // clamp: keep >= 0
        if (lane < 32) atomicMin(out + q, __float_as_uint(v));
    }
}

// ---------- fallback (round-2 VALU kernel) if ws too small ----------
#define FSLICE 512
#define FROWS  512
__global__ __launch_bounds__(256)
void chamfer_dir_kernel(const float* __restrict__ P, const float* __restrict__ Q,
                        unsigned int* __restrict__ out, int Np, int Mp) {
    __shared__ float4 lds[FSLICE];
    const int tid = threadIdx.x;
    const int rowBase = blockIdx.x * FROWS;
    const int b = rowBase / Np;
    const int slice0 = blockIdx.y * FSLICE;
    const float* qs = Q + ((size_t)b * Mp + slice0) * 3;
    #pragma unroll
    for (int i = tid; i < FSLICE; i += 256) {
        const float x = qs[3*i+0], y = qs[3*i+1], z = qs[3*i+2];
        lds[i] = make_float4(x, y, z, fmaf(x, x, fmaf(y, y, z * z)));
    }
    const int q0 = rowBase + tid, q1 = q0 + 256;
    const float* p0 = P + (size_t)q0 * 3;
    const float* p1 = P + (size_t)q1 * 3;
    const float x0=p0[0], y0=p0[1], z0=p0[2], x1=p1[0], y1=p1[1], z1=p1[2];
    const float m2x0=-2*x0, m2y0=-2*y0, m2z0=-2*z0, m2x1=-2*x1, m2y1=-2*y1, m2z1=-2*z1;
    const float sqp0 = fmaf(x0,x0,fmaf(y0,y0,z0*z0));
    const float sqp1 = fmaf(x1,x1,fmaf(y1,y1,z1*z1));
    __syncthreads();
    float best0 = 3.0e38f, best1 = 3.0e38f;
    #pragma unroll 4
    for (int j = 0; j < FSLICE; j += 2) {
        const float4 a = lds[j], c = lds[j+1];
        const float d00 = fmaf(m2x0,a.x,fmaf(m2y0,a.y,fmaf(m2z0,a.z,a.w)));
        const float d01 = fmaf(m2x0,c.x,fmaf(m2y0,c.y,fmaf(m2z0,c.z,c.w)));
        best0 = fminf(fminf(d00,d01), best0);
        const float d10 = fmaf(m2x1,a.x,fmaf(m2y1,a.y,fmaf(m2z1,a.z,a.w)));
        const float d11 = fmaf(m2x1,c.x,fmaf(m2y1,c.y,fmaf(m2z1,c.z,c.w)));
        best1 = fminf(fminf(d10,d11), best1);
    }
    atomicMin(out + q0, __float_as_uint(fmaxf(best0 + sqp0, 0.f)));
    atomicMin(out + q1, __float_as_uint(fmaxf(best1 + sqp1, 0.f)));
}

extern "C" void kernel_launch(void* const* d_in, const int* in_sizes, int n_in,
                              void* d_out, int out_size, void* d_ws, size_t ws_size,
                              hipStream_t stream) {
    const float* in1 = (const float*)d_in[0];   // [B, N, 3]
    const float* in2 = (const float*)d_in[1];   // [B, M, 3]
    const int B = 8;
    const int N = in_sizes[0] / (B * 3);
    const int M = in_sizes[1] / (B * 3);
    const int P1 = B * N, P2 = B * M;
    unsigned int* out = (unsigned int*)d_out;

    const size_t packBytes1 = (size_t)P1 * 32, packBytes2 = (size_t)P2 * 32;
    const size_t need = 2*packBytes1 + 2*packBytes2 + (size_t)(P1+P2)*4;

    if (ws_size >= need && N == M) {
        char* w = (char*)d_ws;
        ushort* A1 = (ushort*)(w);
        ushort* B1 = (ushort*)(w + packBytes1);
        ushort* A2 = (ushort*)(w + 2*packBytes1);
        ushort* B2 = (ushort*)(w + 2*packBytes1 + packBytes2);
        float*  S1 = (float*) (w + 2*packBytes1 + 2*packBytes2);
        float*  S2 = (float*) (w + 2*packBytes1 + 2*packBytes2 + (size_t)P1*4);

        pack_all_kernel<<<(P1 + P2 + 255)/256, 256, 0, stream>>>(
            in1, in2, A1, B1, S1, A2, B2, S2, out, P1, P2);

        // z=0: dist1 (queries=input1, targets=input2); z=1: dist2
        dim3 g(P1 / QPB, M / TSLICE, 2);
        chamfer_mfma_kernel<<<g, 256, 0, stream>>>(
            A2, B1, S1, out,        // dir 1
            A1, B2, S2, out + P1,   // dir 2
            N, M);
    } else {
        hipMemsetAsync(d_out, 0x7F, (size_t)out_size * sizeof(float), stream);
        dim3 g1(P1 / FROWS, M / FSLICE);
        chamfer_dir_kernel<<<g1, 256, 0, stream>>>(in1, in2, out, N, M);
        dim3 g2(P2 / FROWS, N / FSLICE);
        chamfer_dir_kernel<<<g2, 256, 0, stream>>>(in2, in1, out + P1, M, N);
    }
}